// Round 9
// baseline (149.154 us; speedup 1.0000x reference)
//
#include <hip/hip_runtime.h>
#include <stdint.h>

#define OBS 15
#define NTOT 50000
#define HDIM 64
#define NPB 16      // neighbors per block (50000 = 3125 * 16, exact)
#define NBLK_N 3125 // neighbor blocks; blockIdx 0 runs the target LSTM

typedef __attribute__((ext_vector_type(8))) short short8;
typedef __attribute__((ext_vector_type(4))) float f32x4;
typedef __attribute__((ext_vector_type(4))) unsigned int u32x4;

#define KLOG2E 1.4426950408889634f   // log2(e)
#define KLOG2E2 2.8853900817779268f  // 2*log2(e)

static __device__ __forceinline__ unsigned short f2bf(float f) {
  unsigned u = __float_as_uint(f);
  u += 0x7fff + ((u >> 16) & 1);
  return (unsigned short)(u >> 16);
}
static __device__ __forceinline__ float bf2f(unsigned short b) {
  return __uint_as_float(((unsigned)b) << 16);
}

#if __has_builtin(__builtin_amdgcn_exp2f)
#define EXP2F(x) __builtin_amdgcn_exp2f(x)
#else
#define EXP2F(x) exp2f(x)
#endif
#if __has_builtin(__builtin_amdgcn_rcpf)
#define RCPF(x) __builtin_amdgcn_rcpf(x)
#else
#define RCPF(x) (1.0f / (x))
#endif

static __device__ __forceinline__ float sigm(float x) {
  return RCPF(1.0f + EXP2F(-KLOG2E * x));
}
static __device__ __forceinline__ float tanh_(float x) {
  return 2.0f * RCPF(1.0f + EXP2F(-KLOG2E2 * x)) - 1.0f;
}

// LDS ushort index: row r (0..15), 8-ushort block cb (0..7), swizzled.
static __device__ __forceinline__ int hidx(int r, int cb) {
  return r * 64 + ((cb ^ (r & 7)) << 3);
}

// Prep: zero social + build the pre-scaled hi/lo bf16 W_hh tables ONCE.
// Values bit-identical to the inline LOADB path (same f2bf formula/scale).
__global__ __launch_bounds__(256) void k_prep(
    const float* __restrict__ W_hh, float* __restrict__ social,
    unsigned short* __restrict__ whi, unsigned short* __restrict__ wlo) {
  const int gid = blockIdx.x * 256 + threadIdx.x;  // 64 blocks -> 16384
  if (gid < 1024) social[gid] = 0.0f;
  const int g = gid >> 6;  // gate row 0..255
  const float sc = ((g >> 6) == 2) ? -KLOG2E2 : -KLOG2E;
  const float wv = W_hh[gid] * sc;
  const unsigned short hi = f2bf(wv);
  const unsigned short lo = f2bf(wv - bf2f(hi));
  whi[gid] = hi;
  wlo[gid] = lo;
}

__global__ void k_zero(float* social) {
  social[threadIdx.x] = 0.0f;  // fallback when workspace too small for tables
}

#define MFMA_BF16 __builtin_amdgcn_mfma_f32_16x16x32_bf16

// ROUND-9: the 128-reg fit.  History of the arc:
//  - r8: (256,4) splits the unified budget 64 arch + 64 acc; live arch was 68
//    (4 OVER) -> wholesale spill (WRITE 127 MB) but occupancy rose 25->36%.
//  - The x-fold (BX frags + Ax + walk ptrs) costs ~22 arch regs vs ~12 for
//    the plain VALU acc-init, and round 4 measured it as reg-negative for
//    ~zero wall gain (84->96 VGPR).  REMOVED: back to r0's VALU acc-init
//    with PRE-SCALED bias/W_ih (gates stay in the exp2-scaled domain).
//  - TAB weight tables kept (the -28 arch regs that make the fit possible).
//  - cs-domain single-rcp cell kept (r7, in-kernel win).
// Expected live set: ~56-60 arch + 64 acc <= 128 -> 4 waves/SIMD, 2x TLP
// against the measured ~40% idle issue.  Tripwire: WRITE_SIZE >> 2.5 MB =
// spill -> next round reverts to (256,2).
template <bool TAB>
__global__ __launch_bounds__(256, TAB ? 4 : 2)
void k_neigh(
    const float* __restrict__ tgt,   // 15*1*2
    const float* __restrict__ oth,   // 15*N*2
    const int* __restrict__ mask,    // 15*N
    const float* __restrict__ W_ih,  // 256*2
    const float* __restrict__ b_ih,  // 256
    const float* __restrict__ W_hh,  // 256*64
    const float* __restrict__ b_hh,  // 256
    const unsigned short* __restrict__ whi,  // 256*64 pre-scaled bf16 hi
    const unsigned short* __restrict__ wlo,  // 256*64 pre-scaled bf16 lo
    float* __restrict__ social,      // 16*64, pre-zeroed
    float* __restrict__ ht_out)      // 64 (target-LSTM final h)
{
  __shared__ __align__(16) unsigned short h2[2][NPB][HDIM];  // h as bf16
  __shared__ float xs[OBS][NPB][2];
  __shared__ float tht[HDIM];
  __shared__ float tgb[256];

  const int tid = threadIdx.x;

  if (blockIdx.x == 0) {
    // ---- target LSTM, fp32 exact (raw unscaled weights); dispatched FIRST
    // so it hides under the neighbor grid.  Block-uniform branch.
    const float bias = b_ih[tid] + b_hh[tid];
    const float wi0 = W_ih[tid * 2], wi1 = W_ih[tid * 2 + 1];
    const float4* Wr = (const float4*)&W_hh[tid * 64];
    if (tid < HDIM) tht[tid] = 0.0f;
    float ct = 0.0f;
    __syncthreads();
    for (int t = 0; t < OBS; ++t) {
      const float x0 = tgt[t * 2], x1 = tgt[t * 2 + 1];
      float acc = bias + x0 * wi0 + x1 * wi1;
#pragma unroll 4
      for (int k4 = 0; k4 < 16; ++k4) {
        const float4 wv = Wr[k4];
        const float4 hv = *(const float4*)&tht[k4 * 4];
        acc += wv.x * hv.x + wv.y * hv.y + wv.z * hv.z + wv.w * hv.w;
      }
      tgb[tid] = acc;
      __syncthreads();
      if (tid < HDIM) {
        const float cn =
            sigm(tgb[64 + tid]) * ct + sigm(tgb[tid]) * tanh_(tgb[128 + tid]);
        ct = cn;
        tht[tid] = sigm(tgb[192 + tid]) * tanh_(cn);
      }
      __syncthreads();
    }
    if (tid < HDIM) ht_out[tid] = tht[tid];
    return;
  }

  const int l = tid & 63;
  const int w = tid >> 6;   // wave id 0..3 -> owns gate-col slice w*16..w*16+15
  const int t15 = l & 15;
  const int g4 = l >> 4;
  const int n0 = (blockIdx.x - 1) * NPB;

  // stage xo for this block's 16 neighbors, all steps (coalesced, no tail)
  for (int i = tid; i < OBS * NPB * 2; i += 256) {
    ((float*)xs)[i] = oth[(i >> 5) * (NTOT * 2) + n0 * 2 + (i & 31)];
  }
  // zero h buffer 0
  for (int i = tid; i < NPB * HDIM / 2; i += 256) ((unsigned int*)h2[0])[i] = 0u;

  // persistent B fragments: pre-scaled W_hh^T slices for this wave's gate
  // cols, RNE hi/lo split.  TAB: 16B loads from the k_prep tables.
  short8 Bhi0, Bhi1, Bhi2, Bhi3, Bhi4, Bhi5, Bhi6, Bhi7;
  short8 Blo0, Blo1, Blo2, Blo3, Blo4, Blo5, Blo6, Blo7;
  if constexpr (TAB) {
#define LOADT(q, kt, BH, BL)                                      \
    {                                                             \
      const int base = (q * 64 + w * 16 + t15) * 64 + kt * 32 + g4 * 8; \
      BH = *(const short8*)&whi[base];                            \
      BL = *(const short8*)&wlo[base];                            \
    }
    LOADT(0, 0, Bhi0, Blo0) LOADT(0, 1, Bhi1, Blo1)
    LOADT(1, 0, Bhi2, Blo2) LOADT(1, 1, Bhi3, Blo3)
    LOADT(2, 0, Bhi4, Blo4) LOADT(2, 1, Bhi5, Blo5)
    LOADT(3, 0, Bhi6, Blo6) LOADT(3, 1, Bhi7, Blo7)
#undef LOADT
  } else {
#define LOADB(q, kt, BH, BL, SC)                                              \
    {                                                                         \
      const float* wp = &W_hh[(q * 64 + w * 16 + t15) * 64 + kt * 32 + g4 * 8]; \
      _Pragma("unroll") for (int j = 0; j < 8; ++j) {                         \
        float wv = wp[j] * (SC);                                              \
        unsigned short hi = f2bf(wv);                                         \
        unsigned short lo = f2bf(wv - bf2f(hi));                              \
        BH[j] = (short)hi;                                                    \
        BL[j] = (short)lo;                                                    \
      }                                                                       \
    }
    LOADB(0, 0, Bhi0, Blo0, -KLOG2E)  LOADB(0, 1, Bhi1, Blo1, -KLOG2E)
    LOADB(1, 0, Bhi2, Blo2, -KLOG2E)  LOADB(1, 1, Bhi3, Blo3, -KLOG2E)
    LOADB(2, 0, Bhi4, Blo4, -KLOG2E2) LOADB(2, 1, Bhi5, Blo5, -KLOG2E2)
    LOADB(3, 0, Bhi6, Blo6, -KLOG2E)  LOADB(3, 1, Bhi7, Blo7, -KLOG2E)
#undef LOADB
  }

  // VALU acc-init constants, PRE-SCALED (gates live in the exp2 domain):
  // 12 regs vs the x-fold's ~22 — the swap that makes the 128-reg fit.
  float bias2[4], wih0[4], wih1[4];
#pragma unroll
  for (int q = 0; q < 4; ++q) {
    const float sc = (q == 2) ? -KLOG2E2 : -KLOG2E;
    const int g = q * 64 + w * 16 + t15;
    bias2[q] = (b_ih[g] + b_hh[g]) * sc;
    wih0[q] = W_ih[g * 2 + 0] * sc;
    wih1[q] = W_ih[g * 2 + 1] * sc;
  }

  // cs = -2log2e * c  (c starts at 0)
  f32x4 cs = (f32x4){0.f, 0.f, 0.f, 0.f};
  const float refx = tgt[14 * 2 + 0];
  const float refy = tgt[14 * 2 + 1];

  __syncthreads();

  for (int t = 0; t < OBS; ++t) {
    const int cur = t & 1, nxt = cur ^ 1;
    // A fragments: row t15, k-block (kt*4 + g4), direct bf16 LDS read
    short8 A0 = *(const short8*)&h2[cur][0][hidx(t15, g4)];
    short8 A1 = *(const short8*)&h2[cur][0][hidx(t15, 4 + g4)];

    // acc0 = -log2e*i, acc1 = -log2e*f, acc2 = -2log2e*g, acc3 = -log2e*o
    f32x4 acc0, acc1, acc2, acc3;
#pragma unroll
    for (int r = 0; r < 4; ++r) {
      const int nl = g4 * 4 + r;
      const float xa = xs[t][nl][0], xb = xs[t][nl][1];
      acc0[r] = bias2[0] + xa * wih0[0] + xb * wih1[0];
      acc1[r] = bias2[1] + xa * wih0[1] + xb * wih1[1];
      acc2[r] = bias2[2] + xa * wih0[2] + xb * wih1[2];
      acc3[r] = bias2[3] + xa * wih0[3] + xb * wih1[3];
    }
    acc0 = MFMA_BF16(A0, Bhi0, acc0, 0, 0, 0);
    acc1 = MFMA_BF16(A0, Bhi2, acc1, 0, 0, 0);
    acc2 = MFMA_BF16(A0, Bhi4, acc2, 0, 0, 0);
    acc3 = MFMA_BF16(A0, Bhi6, acc3, 0, 0, 0);
    acc0 = MFMA_BF16(A1, Bhi1, acc0, 0, 0, 0);
    acc1 = MFMA_BF16(A1, Bhi3, acc1, 0, 0, 0);
    acc2 = MFMA_BF16(A1, Bhi5, acc2, 0, 0, 0);
    acc3 = MFMA_BF16(A1, Bhi7, acc3, 0, 0, 0);
    acc0 = MFMA_BF16(A0, Blo0, acc0, 0, 0, 0);
    acc1 = MFMA_BF16(A0, Blo2, acc1, 0, 0, 0);
    acc2 = MFMA_BF16(A0, Blo4, acc2, 0, 0, 0);
    acc3 = MFMA_BF16(A0, Blo6, acc3, 0, 0, 0);
    acc0 = MFMA_BF16(A1, Blo1, acc0, 0, 0, 0);
    acc1 = MFMA_BF16(A1, Blo3, acc1, 0, 0, 0);
    acc2 = MFMA_BF16(A1, Blo5, acc2, 0, 0, 0);
    acc3 = MFMA_BF16(A1, Blo7, acc3, 0, 0, 0);

    // cs-domain fused cell (A=1+ei, B=1+eg, C=1+ef):
    //   cs' = (cs*A*B + K2*(eg-1)*C) * rcp(A*B*C)   [= -2log2e * cn]
    //   ecn = exp2(cs')
    //   h   = (1-ecn) / ((1+eo)(1+ecn))             [= sig(o)*tanh(cn)]
    if (t < OBS - 1) {
#pragma unroll
      for (int r = 0; r < 4; ++r) {
        const float ei = EXP2F(acc0[r]);
        const float ef = EXP2F(acc1[r]);
        const float eg = EXP2F(acc2[r]);
        const float eo = EXP2F(acc3[r]);
        const float A = 1.0f + ei, B = 1.0f + eg, C = 1.0f + ef;
        const float AB = A * B;
        const float rr = RCPF(AB * C);
        const float u = (eg - 1.0f) * C;
        const float csn = (cs[r] * AB + KLOG2E2 * u) * rr;
        cs[r] = csn;
        const float ecn = EXP2F(csn);
        const float ro = RCPF((1.0f + eo) * (1.0f + ecn));
        const float h = (1.0f - ecn) * ro;
        const int n = g4 * 4 + r;
        const int col = w * 16 + t15;
        h2[nxt][0][hidx(n, col >> 3) + (col & 7)] = f2bf(h);
      }
      __syncthreads();
    } else {
      // final step: compute h (fp32) and pool directly
#pragma unroll
      for (int r = 0; r < 4; ++r) {
        const float ei = EXP2F(acc0[r]);
        const float ef = EXP2F(acc1[r]);
        const float eg = EXP2F(acc2[r]);
        const float eo = EXP2F(acc3[r]);
        const float A = 1.0f + ei, B = 1.0f + eg, C = 1.0f + ef;
        const float AB = A * B;
        const float rr = RCPF(AB * C);
        const float u = (eg - 1.0f) * C;
        const float csn = (cs[r] * AB + KLOG2E2 * u) * rr;
        const float ecn = EXP2F(csn);
        const float ro = RCPF((1.0f + eo) * (1.0f + ecn));
        const float h = (1.0f - ecn) * ro;
        const int nl = g4 * 4 + r;
        const int gn = n0 + nl;
        const float rx = xs[OBS - 1][nl][0] - refx;
        const float ry = xs[OBS - 1][nl][1] - refy;
        bool ok = (fabsf(rx) <= 2.0f) && (fabsf(ry) <= 2.0f);
        const int cx = (int)truncf(rx) + 2;  // cw == 1.0
        const int cy = (int)truncf(ry) + 2;
        ok = ok && (cx >= 0) && (cx < 4) && (cy >= 0) && (cy < 4);
        if (ok && mask[(OBS - 1) * NTOT + gn] != 0)
          atomicAdd(&social[(cy * 4 + cx) * HDIM + w * 16 + t15], h);
      }
    }
  }
}

// Slim k_final (verified rounds 1-8): social MLP + readout only.
__global__ __launch_bounds__(512) void k_final(
    const float* __restrict__ W1, const float* __restrict__ b1,
    const float* __restrict__ W2, const float* __restrict__ b2,
    const float* __restrict__ Wc, const float* __restrict__ bc,
    const float* __restrict__ social, const float* __restrict__ ht_g,
    float* __restrict__ out)
{
  __shared__ float sv[1024];
  __shared__ float hid[64];
  __shared__ float comb[64];
  __shared__ float ht[64];

  const int tid = threadIdx.x;
  for (int i = tid; i < 1024; i += 512) sv[i] = social[i];
  if (tid < 64) ht[tid] = ht_g[tid];
  __syncthreads();

  const int wv = tid >> 6, ln = tid & 63;
  for (int o = wv; o < 64; o += 8) {
    float p = 0.0f;
#pragma unroll
    for (int it = 0; it < 16; ++it) {
      const int j = it * 64 + ln;
      p += sv[j] * W1[o * 1024 + j];
    }
#pragma unroll
    for (int off = 32; off > 0; off >>= 1) p += __shfl_down(p, off);
    if (ln == 0) hid[o] = fmaxf(p + b1[o], 0.0f);
  }
  __syncthreads();
  for (int o = wv; o < 64; o += 8) {
    float p = hid[ln] * W2[o * 64 + ln];
#pragma unroll
    for (int off = 32; off > 0; off >>= 1) p += __shfl_down(p, off);
    if (ln == 0) comb[o] = ht[o] + p + b2[o];
  }
  __syncthreads();
  if (wv < 2) {
    float p = comb[ln] * Wc[wv * 64 + ln];
#pragma unroll
    for (int off = 32; off > 0; off >>= 1) p += __shfl_down(p, off);
    if (ln == 0) out[wv] = p + bc[wv];
  }
}

extern "C" void kernel_launch(void* const* d_in, const int* in_sizes, int n_in,
                              void* d_out, int out_size, void* d_ws, size_t ws_size,
                              hipStream_t stream) {
  const float* tgt = (const float*)d_in[0];
  const float* oth = (const float*)d_in[1];
  const int* mask = (const int*)d_in[2];
  const float* W_ih = (const float*)d_in[3];
  const float* b_ih = (const float*)d_in[4];
  const float* W_hh = (const float*)d_in[5];
  const float* b_hh = (const float*)d_in[6];
  const float* W1 = (const float*)d_in[7];
  const float* b1 = (const float*)d_in[8];
  const float* W2 = (const float*)d_in[9];
  const float* b2 = (const float*)d_in[10];
  const float* Wc = (const float*)d_in[11];
  const float* bc = (const float*)d_in[12];
  float* social = (float*)d_ws;                         // bytes [0, 4096)
  float* ht = social + 1024;                            // bytes [4096, 4352)
  unsigned short* whi = (unsigned short*)((char*)d_ws + 8192);  // 32 KB
  unsigned short* wlo = whi + 256 * 64;                         // 32 KB
  float* out = (float*)d_out;

  const bool tab = ws_size >= (size_t)(8192 + 2 * 256 * 64 * sizeof(unsigned short));

  if (tab) {
    hipLaunchKernelGGL(k_prep, dim3(64), dim3(256), 0, stream,
                       W_hh, social, whi, wlo);
    hipLaunchKernelGGL((k_neigh<true>), dim3(NBLK_N + 1), dim3(256), 0, stream,
                       tgt, oth, mask, W_ih, b_ih, W_hh, b_hh, whi, wlo,
                       social, ht);
  } else {
    hipLaunchKernelGGL(k_zero, dim3(1), dim3(1024), 0, stream, social);
    hipLaunchKernelGGL((k_neigh<false>), dim3(NBLK_N + 1), dim3(256), 0, stream,
                       tgt, oth, mask, W_ih, b_ih, W_hh, b_hh, whi, wlo,
                       social, ht);
  }
  hipLaunchKernelGGL(k_final, dim3(1), dim3(512), 0, stream,
                     W1, b1, W2, b2, Wc, bc, social, ht, out);
}

// Round 10
// 123.426 us; speedup vs baseline: 1.2084x; 1.2084x over previous
//
#include <hip/hip_runtime.h>
#include <stdint.h>

#define OBS 15
#define NTOT 50000
#define HDIM 64
#define NPB 16      // neighbors per block (50000 = 3125 * 16, exact)
#define NBLK_N 3125 // neighbor blocks; blockIdx 0 runs the target LSTM

typedef __attribute__((ext_vector_type(8))) short short8;
typedef __attribute__((ext_vector_type(4))) float f32x4;

#define KLOG2E 1.4426950408889634f   // log2(e)
#define KLOG2E2 2.8853900817779268f  // 2*log2(e)

static __device__ __forceinline__ unsigned short f2bf(float f) {
  unsigned u = __float_as_uint(f);
  u += 0x7fff + ((u >> 16) & 1);
  return (unsigned short)(u >> 16);
}
static __device__ __forceinline__ float bf2f(unsigned short b) {
  return __uint_as_float(((unsigned)b) << 16);
}

#if __has_builtin(__builtin_amdgcn_exp2f)
#define EXP2F(x) __builtin_amdgcn_exp2f(x)
#else
#define EXP2F(x) exp2f(x)
#endif
#if __has_builtin(__builtin_amdgcn_rcpf)
#define RCPF(x) __builtin_amdgcn_rcpf(x)
#else
#define RCPF(x) (1.0f / (x))
#endif

static __device__ __forceinline__ float sigm(float x) {
  return RCPF(1.0f + EXP2F(-KLOG2E * x));
}
static __device__ __forceinline__ float tanh_(float x) {
  return 2.0f * RCPF(1.0f + EXP2F(-KLOG2E2 * x)) - 1.0f;
}

// LDS ushort index: row r (0..15), 8-ushort block cb (0..7), swizzled.
static __device__ __forceinline__ int hidx(int r, int cb) {
  return r * 64 + ((cb ^ (r & 7)) << 3);
}

#define MFMA_BF16 __builtin_amdgcn_mfma_f32_16x16x32_bf16

// ROUND-10 CONSOLIDATION.  Session ledger:
//  - Timed-total best was r6 (120.5 us); profiled per-dispatch durations
//    proved unreliable cross-round (r7: profiled k_neigh -4 us, timed +12).
//  - Occupancy arc CLOSED: (256,4) spills at any achievable arch-reg count
//    (r8: 127 MB scratch writes; r9: 27 MB).  64 W-frag regs + ~70 arch > 128.
//  - ILP arcs CLOSED: 2-group per wave (r5) and transposed-MFMA (r1/r2) both
//    regressed; cross-block TLP at NPB=16/3126 blocks is the right shape.
//  - Kernel is latency-bound (HBM 0.6%, MfmaUtil 20%, VALU-busy ~50 us of
//    ~120): 15 barrier-synced steps x 3125 blocks at 2 waves/SIMD.
// This round: one non-template kernel (stable codegen), (256,2), with every
// independently-verified piece: inline pre-scaled LOADB, pre-scaled VALU
// acc-init (r9), cs-domain single-rcp cell (r7/r9, absmax 0.0), xs float
// staging (0 bank conflicts, r9), target-LSTM at blockIdx 0, slim k_final,
// social zeroed via hipMemsetAsync (one fewer launch).
__global__ __launch_bounds__(256, 2)
void k_neigh(
    const float* __restrict__ tgt,   // 15*1*2
    const float* __restrict__ oth,   // 15*N*2
    const int* __restrict__ mask,    // 15*N
    const float* __restrict__ W_ih,  // 256*2
    const float* __restrict__ b_ih,  // 256
    const float* __restrict__ W_hh,  // 256*64
    const float* __restrict__ b_hh,  // 256
    float* __restrict__ social,      // 16*64, pre-zeroed
    float* __restrict__ ht_out)      // 64 (target-LSTM final h)
{
  __shared__ __align__(16) unsigned short h2[2][NPB][HDIM];  // h as bf16
  __shared__ float xs[OBS][NPB][2];
  __shared__ float tht[HDIM];
  __shared__ float tgb[256];

  const int tid = threadIdx.x;

  if (blockIdx.x == 0) {
    // ---- target LSTM, fp32 exact (raw unscaled weights); dispatched FIRST
    // so it hides under the neighbor grid.  Block-uniform branch.
    const float bias = b_ih[tid] + b_hh[tid];
    const float wi0 = W_ih[tid * 2], wi1 = W_ih[tid * 2 + 1];
    const float4* Wr = (const float4*)&W_hh[tid * 64];
    if (tid < HDIM) tht[tid] = 0.0f;
    float ct = 0.0f;
    __syncthreads();
    for (int t = 0; t < OBS; ++t) {
      const float x0 = tgt[t * 2], x1 = tgt[t * 2 + 1];
      float acc = bias + x0 * wi0 + x1 * wi1;
#pragma unroll 4
      for (int k4 = 0; k4 < 16; ++k4) {
        const float4 wv = Wr[k4];
        const float4 hv = *(const float4*)&tht[k4 * 4];
        acc += wv.x * hv.x + wv.y * hv.y + wv.z * hv.z + wv.w * hv.w;
      }
      tgb[tid] = acc;
      __syncthreads();
      if (tid < HDIM) {
        const float cn =
            sigm(tgb[64 + tid]) * ct + sigm(tgb[tid]) * tanh_(tgb[128 + tid]);
        ct = cn;
        tht[tid] = sigm(tgb[192 + tid]) * tanh_(cn);
      }
      __syncthreads();
    }
    if (tid < HDIM) ht_out[tid] = tht[tid];
    return;
  }

  const int l = tid & 63;
  const int w = tid >> 6;   // wave id 0..3 -> owns gate-col slice w*16..w*16+15
  const int t15 = l & 15;
  const int g4 = l >> 4;
  const int n0 = (blockIdx.x - 1) * NPB;

  // stage xo for this block's 16 neighbors, all steps (coalesced, no tail)
  for (int i = tid; i < OBS * NPB * 2; i += 256) {
    ((float*)xs)[i] = oth[(i >> 5) * (NTOT * 2) + n0 * 2 + (i & 31)];
  }
  // zero h buffer 0
  for (int i = tid; i < NPB * HDIM / 2; i += 256) ((unsigned int*)h2[0])[i] = 0u;

  // persistent B fragments: W_hh^T slices for this wave's gate cols,
  // PRE-SCALED by the consuming activation's exp2 constant, RNE hi/lo split.
  short8 Bhi0, Bhi1, Bhi2, Bhi3, Bhi4, Bhi5, Bhi6, Bhi7;
  short8 Blo0, Blo1, Blo2, Blo3, Blo4, Blo5, Blo6, Blo7;
#define LOADB(q, kt, BH, BL, SC)                                              \
  {                                                                           \
    const float* wp = &W_hh[(q * 64 + w * 16 + t15) * 64 + kt * 32 + g4 * 8]; \
    _Pragma("unroll") for (int j = 0; j < 8; ++j) {                           \
      float wv = wp[j] * (SC);                                                \
      unsigned short hi = f2bf(wv);                                           \
      unsigned short lo = f2bf(wv - bf2f(hi));                                \
      BH[j] = (short)hi;                                                      \
      BL[j] = (short)lo;                                                      \
    }                                                                         \
  }
  LOADB(0, 0, Bhi0, Blo0, -KLOG2E)  LOADB(0, 1, Bhi1, Blo1, -KLOG2E)
  LOADB(1, 0, Bhi2, Blo2, -KLOG2E)  LOADB(1, 1, Bhi3, Blo3, -KLOG2E)
  LOADB(2, 0, Bhi4, Blo4, -KLOG2E2) LOADB(2, 1, Bhi5, Blo5, -KLOG2E2)
  LOADB(3, 0, Bhi6, Blo6, -KLOG2E)  LOADB(3, 1, Bhi7, Blo7, -KLOG2E)
#undef LOADB

  // VALU acc-init constants, PRE-SCALED (gates live in the exp2 domain).
  float bias2[4], wih0[4], wih1[4];
#pragma unroll
  for (int q = 0; q < 4; ++q) {
    const float sc = (q == 2) ? -KLOG2E2 : -KLOG2E;
    const int g = q * 64 + w * 16 + t15;
    bias2[q] = (b_ih[g] + b_hh[g]) * sc;
    wih0[q] = W_ih[g * 2 + 0] * sc;
    wih1[q] = W_ih[g * 2 + 1] * sc;
  }

  // cs = -2log2e * c  (c starts at 0)
  f32x4 cs = (f32x4){0.f, 0.f, 0.f, 0.f};
  const float refx = tgt[14 * 2 + 0];
  const float refy = tgt[14 * 2 + 1];

  __syncthreads();

  for (int t = 0; t < OBS; ++t) {
    const int cur = t & 1, nxt = cur ^ 1;
    // A fragments: row t15, k-block (kt*4 + g4), direct bf16 LDS read
    short8 A0 = *(const short8*)&h2[cur][0][hidx(t15, g4)];
    short8 A1 = *(const short8*)&h2[cur][0][hidx(t15, 4 + g4)];

    // acc0 = -log2e*i, acc1 = -log2e*f, acc2 = -2log2e*g, acc3 = -log2e*o
    f32x4 acc0, acc1, acc2, acc3;
#pragma unroll
    for (int r = 0; r < 4; ++r) {
      const int nl = g4 * 4 + r;
      const float xa = xs[t][nl][0], xb = xs[t][nl][1];
      acc0[r] = bias2[0] + xa * wih0[0] + xb * wih1[0];
      acc1[r] = bias2[1] + xa * wih0[1] + xb * wih1[1];
      acc2[r] = bias2[2] + xa * wih0[2] + xb * wih1[2];
      acc3[r] = bias2[3] + xa * wih0[3] + xb * wih1[3];
    }
    acc0 = MFMA_BF16(A0, Bhi0, acc0, 0, 0, 0);
    acc1 = MFMA_BF16(A0, Bhi2, acc1, 0, 0, 0);
    acc2 = MFMA_BF16(A0, Bhi4, acc2, 0, 0, 0);
    acc3 = MFMA_BF16(A0, Bhi6, acc3, 0, 0, 0);
    acc0 = MFMA_BF16(A1, Bhi1, acc0, 0, 0, 0);
    acc1 = MFMA_BF16(A1, Bhi3, acc1, 0, 0, 0);
    acc2 = MFMA_BF16(A1, Bhi5, acc2, 0, 0, 0);
    acc3 = MFMA_BF16(A1, Bhi7, acc3, 0, 0, 0);
    acc0 = MFMA_BF16(A0, Blo0, acc0, 0, 0, 0);
    acc1 = MFMA_BF16(A0, Blo2, acc1, 0, 0, 0);
    acc2 = MFMA_BF16(A0, Blo4, acc2, 0, 0, 0);
    acc3 = MFMA_BF16(A0, Blo6, acc3, 0, 0, 0);
    acc0 = MFMA_BF16(A1, Blo1, acc0, 0, 0, 0);
    acc1 = MFMA_BF16(A1, Blo3, acc1, 0, 0, 0);
    acc2 = MFMA_BF16(A1, Blo5, acc2, 0, 0, 0);
    acc3 = MFMA_BF16(A1, Blo7, acc3, 0, 0, 0);

    // cs-domain fused cell (A=1+ei, B=1+eg, C=1+ef):
    //   cs' = (cs*A*B + K2*(eg-1)*C) * rcp(A*B*C)   [= -2log2e * cn]
    //   ecn = exp2(cs')
    //   h   = (1-ecn) / ((1+eo)(1+ecn))             [= sig(o)*tanh(cn)]
    if (t < OBS - 1) {
#pragma unroll
      for (int r = 0; r < 4; ++r) {
        const float ei = EXP2F(acc0[r]);
        const float ef = EXP2F(acc1[r]);
        const float eg = EXP2F(acc2[r]);
        const float eo = EXP2F(acc3[r]);
        const float A = 1.0f + ei, B = 1.0f + eg, C = 1.0f + ef;
        const float AB = A * B;
        const float rr = RCPF(AB * C);
        const float u = (eg - 1.0f) * C;
        const float csn = (cs[r] * AB + KLOG2E2 * u) * rr;
        cs[r] = csn;
        const float ecn = EXP2F(csn);
        const float ro = RCPF((1.0f + eo) * (1.0f + ecn));
        const float h = (1.0f - ecn) * ro;
        const int n = g4 * 4 + r;
        const int col = w * 16 + t15;
        h2[nxt][0][hidx(n, col >> 3) + (col & 7)] = f2bf(h);
      }
      __syncthreads();
    } else {
      // final step: compute h (fp32) and pool directly
#pragma unroll
      for (int r = 0; r < 4; ++r) {
        const float ei = EXP2F(acc0[r]);
        const float ef = EXP2F(acc1[r]);
        const float eg = EXP2F(acc2[r]);
        const float eo = EXP2F(acc3[r]);
        const float A = 1.0f + ei, B = 1.0f + eg, C = 1.0f + ef;
        const float AB = A * B;
        const float rr = RCPF(AB * C);
        const float u = (eg - 1.0f) * C;
        const float csn = (cs[r] * AB + KLOG2E2 * u) * rr;
        const float ecn = EXP2F(csn);
        const float ro = RCPF((1.0f + eo) * (1.0f + ecn));
        const float h = (1.0f - ecn) * ro;
        const int nl = g4 * 4 + r;
        const int gn = n0 + nl;
        const float rx = xs[OBS - 1][nl][0] - refx;
        const float ry = xs[OBS - 1][nl][1] - refy;
        bool ok = (fabsf(rx) <= 2.0f) && (fabsf(ry) <= 2.0f);
        const int cx = (int)truncf(rx) + 2;  // cw == 1.0
        const int cy = (int)truncf(ry) + 2;
        ok = ok && (cx >= 0) && (cx < 4) && (cy >= 0) && (cy < 4);
        if (ok && mask[(OBS - 1) * NTOT + gn] != 0)
          atomicAdd(&social[(cy * 4 + cx) * HDIM + w * 16 + t15], h);
      }
    }
  }
}

// Slim k_final (verified rounds 1-9): social MLP + readout only.
__global__ __launch_bounds__(512) void k_final(
    const float* __restrict__ W1, const float* __restrict__ b1,
    const float* __restrict__ W2, const float* __restrict__ b2,
    const float* __restrict__ Wc, const float* __restrict__ bc,
    const float* __restrict__ social, const float* __restrict__ ht_g,
    float* __restrict__ out)
{
  __shared__ float sv[1024];
  __shared__ float hid[64];
  __shared__ float comb[64];
  __shared__ float ht[64];

  const int tid = threadIdx.x;
  for (int i = tid; i < 1024; i += 512) sv[i] = social[i];
  if (tid < 64) ht[tid] = ht_g[tid];
  __syncthreads();

  const int wv = tid >> 6, ln = tid & 63;
  for (int o = wv; o < 64; o += 8) {
    float p = 0.0f;
#pragma unroll
    for (int it = 0; it < 16; ++it) {
      const int j = it * 64 + ln;
      p += sv[j] * W1[o * 1024 + j];
    }
#pragma unroll
    for (int off = 32; off > 0; off >>= 1) p += __shfl_down(p, off);
    if (ln == 0) hid[o] = fmaxf(p + b1[o], 0.0f);
  }
  __syncthreads();
  for (int o = wv; o < 64; o += 8) {
    float p = hid[ln] * W2[o * 64 + ln];
#pragma unroll
    for (int off = 32; off > 0; off >>= 1) p += __shfl_down(p, off);
    if (ln == 0) comb[o] = ht[o] + p + b2[o];
  }
  __syncthreads();
  if (wv < 2) {
    float p = comb[ln] * Wc[wv * 64 + ln];
#pragma unroll
    for (int off = 32; off > 0; off >>= 1) p += __shfl_down(p, off);
    if (ln == 0) out[wv] = p + bc[wv];
  }
}

extern "C" void kernel_launch(void* const* d_in, const int* in_sizes, int n_in,
                              void* d_out, int out_size, void* d_ws, size_t ws_size,
                              hipStream_t stream) {
  const float* tgt = (const float*)d_in[0];
  const float* oth = (const float*)d_in[1];
  const int* mask = (const int*)d_in[2];
  const float* W_ih = (const float*)d_in[3];
  const float* b_ih = (const float*)d_in[4];
  const float* W_hh = (const float*)d_in[5];
  const float* b_hh = (const float*)d_in[6];
  const float* W1 = (const float*)d_in[7];
  const float* b1 = (const float*)d_in[8];
  const float* W2 = (const float*)d_in[9];
  const float* b2 = (const float*)d_in[10];
  const float* Wc = (const float*)d_in[11];
  const float* bc = (const float*)d_in[12];
  float* social = (float*)d_ws;          // ws[0..1023]
  float* ht = social + 1024;             // ws[1024..1087] (target-LSTM h)
  float* out = (float*)d_out;

  // social zeroed via memset node (graph-capturable; harness reset() uses it)
  hipMemsetAsync(social, 0, 16 * 64 * sizeof(float), stream);
  hipLaunchKernelGGL(k_neigh, dim3(NBLK_N + 1), dim3(256), 0, stream,
                     tgt, oth, mask, W_ih, b_ih, W_hh, b_hh, social, ht);
  hipLaunchKernelGGL(k_final, dim3(1), dim3(512), 0, stream,
                     W1, b1, W2, b2, Wc, bc, social, ht, out);
}